// Round 1
// baseline (223.341 us; speedup 1.0000x reference)
//
#include <hip/hip_runtime.h>
#include <hip/hip_bf16.h>
#include <math.h>

#define N_TOK 32768
#define DDIM 1024
#define NEXP 16
#define TOK_PER_BLK 64
#define DC 128
#define THREADS 256

// out layout (floats): [0,65536) top2 gates, [65536,131072) top2 indices (as float),
// [131072,131088) load
__global__ __launch_bounds__(THREADS) void router_main(
    const float* __restrict__ x, const float* __restrict__ noise,
    const float* __restrict__ Wg, const float* __restrict__ Wn,
    float* __restrict__ out_gates, float* __restrict__ out_idx,
    float* __restrict__ out_load)
{
    __shared__ float tile[TOK_PER_BLK * DC];   // 32 KB, XOR-swizzled
    __shared__ float res[4][TOK_PER_BLK][8];   // 8 KB: per-wave dot results

    const int tid  = threadIdx.x;
    const int lane = tid & 63;
    const int w    = __builtin_amdgcn_readfirstlane(tid >> 6); // wave id, SGPR
    const int tokBase = blockIdx.x * TOK_PER_BLK;

    // wave 0: gate experts 0-7, wave 1: gate 8-15, wave 2: noise 0-7, wave 3: noise 8-15
    const float* Wrows = ((w & 2) ? Wn : Wg) + (size_t)(w & 1) * (8 * DDIM);

    float acc[8];
#pragma unroll
    for (int e = 0; e < 8; ++e) acc[e] = 0.0f;

    const int rowOff = lane * (DC * 4);        // 512 B per token row
    const int swz    = (lane & 31) << 4;

    for (int k0 = 0; k0 < DDIM; k0 += DC) {
        // ---- stage x tile: 32 KB total, 8 x 1KB global_load_lds per wave ----
#pragma unroll
        for (int i = 0; i < 8; ++i) {
            const int instr = w * 8 + i;              // 0..31
            const int P = instr * 1024 + lane * 16;   // physical byte offset (lane's slot)
            const int L = P ^ (((P >> 9) & 31) << 4); // logical byte offset (involution)
            const int t  = L >> 9;                    // token row
            const int dl = (L & 511) >> 2;            // d within chunk
            const float* src = x + (size_t)(tokBase + t) * DDIM + k0 + dl;
            __builtin_amdgcn_global_load_lds(
                (const __attribute__((address_space(1))) void*)src,
                (__attribute__((address_space(3))) void*)((char*)tile + instr * 1024),
                16, 0, 0);
        }
        __syncthreads();

        // ---- compute: acc[e] += x[lane][k] * W[e][k], W via scalar loads ----
#pragma unroll
        for (int kk = 0; kk < DC; kk += 4) {
            const int P = (rowOff + kk * 4) ^ swz;
            const float4 xv = *(const float4*)((const char*)tile + P);
            const float* wp = Wrows + k0 + kk;
#pragma unroll
            for (int e = 0; e < 8; ++e) {
                acc[e] = fmaf(xv.x, wp[e * DDIM + 0], acc[e]);
                acc[e] = fmaf(xv.y, wp[e * DDIM + 1], acc[e]);
                acc[e] = fmaf(xv.z, wp[e * DDIM + 2], acc[e]);
                acc[e] = fmaf(xv.w, wp[e * DDIM + 3], acc[e]);
            }
        }
        __syncthreads();
    }

    // ---- gather the 4 wave-octets per token ----
#pragma unroll
    for (int e = 0; e < 8; ++e) res[w][lane][e] = acc[e];
    __syncthreads();

    if (tid < TOK_PER_BLK) {
        const int t = tid;
        const int tok = tokBase + t;

        float nz[16];
#pragma unroll
        for (int j = 0; j < 4; ++j) {
            const float4 v = *(const float4*)(noise + (size_t)tok * 16 + j * 4);
            nz[j * 4 + 0] = v.x; nz[j * 4 + 1] = v.y;
            nz[j * 4 + 2] = v.z; nz[j * 4 + 3] = v.w;
        }

        float logit[16];
#pragma unroll
        for (int e = 0; e < 16; ++e) {
            const float cl = res[e >> 3][t][e & 7];
            const float nl = res[2 + (e >> 3)][t][e & 7];
            const float sp = fmaxf(nl, 0.0f) + log1pf(expf(-fabsf(nl)));
            logit[e] = cl + nz[e] * sp * 0.01f;
        }

        float m = logit[0];
#pragma unroll
        for (int e = 1; e < 16; ++e) m = fmaxf(m, logit[e]);

        float g[16];
        float s = 0.0f;
#pragma unroll
        for (int e = 0; e < 16; ++e) { g[e] = expf(logit[e] - m); s += g[e]; }
        const float inv = 1.0f / s;
#pragma unroll
        for (int e = 0; e < 16; ++e) g[e] *= inv;

        // top-2, strict > so ties keep the lower index (matches lax.top_k)
        float v1 = -1.0f, v2 = -1.0f;
        int i1 = 0, i2 = 0;
#pragma unroll
        for (int e = 0; e < 16; ++e) {
            const float ge = g[e];
            if (ge > v1)      { v2 = v1; i2 = i1; v1 = ge; i1 = e; }
            else if (ge > v2) { v2 = ge; i2 = e; }
        }
        const float den = v1 + v2 + 1e-8f;
        out_gates[(size_t)tok * 2 + 0] = v1 / den;
        out_gates[(size_t)tok * 2 + 1] = v2 / den;
        out_idx[(size_t)tok * 2 + 0] = (float)i1;
        out_idx[(size_t)tok * 2 + 1] = (float)i2;

        // load = sum over tokens of gates: reduce across the 64 lanes of wave 0
#pragma unroll
        for (int e = 0; e < 16; ++e) {
            float v = g[e];
            for (int off = 32; off; off >>= 1) v += __shfl_xor(v, off, 64);
            if (lane == 0) atomicAdd(&out_load[e], v);
        }
    }
}

extern "C" void kernel_launch(void* const* d_in, const int* in_sizes, int n_in,
                              void* d_out, int out_size, void* d_ws, size_t ws_size,
                              hipStream_t stream) {
    (void)in_sizes; (void)n_in; (void)d_ws; (void)ws_size; (void)out_size;
    const float* x     = (const float*)d_in[0];
    const float* noise = (const float*)d_in[1];
    const float* Wg    = (const float*)d_in[2];
    const float* Wn    = (const float*)d_in[3];

    float* out       = (float*)d_out;
    float* out_gates = out;
    float* out_idx   = out + (size_t)N_TOK * 2;
    float* out_load  = out + (size_t)N_TOK * 4;

    // load region is accumulated with atomics -> zero it every call
    hipMemsetAsync(out_load, 0, NEXP * sizeof(float), stream);

    router_main<<<N_TOK / TOK_PER_BLK, THREADS, 0, stream>>>(
        x, noise, Wg, Wn, out_gates, out_idx, out_load);
}

// Round 2
// 222.418 us; speedup vs baseline: 1.0041x; 1.0041x over previous
//
#include <hip/hip_runtime.h>
#include <hip/hip_bf16.h>
#include <math.h>

#define N_TOK 32768
#define DDIM 1024
#define NEXP 16
#define TOK_PER_BLK 64
#define DC 128
#define NCHUNK (DDIM / DC)
#define THREADS 256

// out layout (floats): [0,65536) top2 gates, [65536,131072) top2 indices (as float),
// [131072,131088) load
__global__ __launch_bounds__(THREADS) void router_main(
    const float* __restrict__ x, const float* __restrict__ noise,
    const float* __restrict__ Wg, const float* __restrict__ Wn,
    float* __restrict__ out_gates, float* __restrict__ out_idx,
    float* __restrict__ out_load)
{
    __shared__ float tile[2][TOK_PER_BLK * DC];  // 2 x 32 KB, XOR-swizzled
    __shared__ float res[4][TOK_PER_BLK][8];     // 8 KB: per-wave dot results

    const int tid  = threadIdx.x;
    const int lane = tid & 63;
    const int w    = __builtin_amdgcn_readfirstlane(tid >> 6); // wave id, SGPR
    const int tokBase = blockIdx.x * TOK_PER_BLK;

    // wave 0: gate experts 0-7, wave 1: gate 8-15, wave 2: noise 0-7, wave 3: noise 8-15
    const float* Wrows = ((w & 2) ? Wn : Wg) + (size_t)(w & 1) * (8 * DDIM);

    float acc[8];
#pragma unroll
    for (int e = 0; e < 8; ++e) acc[e] = 0.0f;

    const int rowOff = lane * (DC * 4);        // 512 B per token row
    const int swz    = (lane & 31) << 4;

    // ---- staging helper (wave-uniform dest + pre-swizzled per-lane source) ----
    auto stage = [&](int buf, int c) {
#pragma unroll
        for (int i = 0; i < 8; ++i) {
            const int instr = w * 8 + i;              // 0..31
            const int P = instr * 1024 + lane * 16;   // physical byte offset in tile
            const int L = P ^ (((P >> 9) & 31) << 4); // logical byte offset (involution)
            const int t  = L >> 9;                    // token row
            const int dl = (L & 511) >> 2;            // float idx within row
            const float* src = x + (size_t)(tokBase + t) * DDIM + c * DC + dl;
            __builtin_amdgcn_global_load_lds(
                (const __attribute__((address_space(1))) void*)src,
                (__attribute__((address_space(3))) void*)((char*)&tile[buf][0] + instr * 1024),
                16, 0, 0);
        }
    };

    stage(0, 0);
    __syncthreads();

    for (int c = 0; c < NCHUNK; ++c) {
        const int cur = c & 1;
        if (c + 1 < NCHUNK) stage(cur ^ 1, c + 1);   // prefetch next chunk

        const char* tbase = (const char*)&tile[cur][0];

        // ---- compute chunk in 4 sub-chunks of 32 k:
        //      phase 1: LDS -> 32 VGPRs, phase 2: pure s_load(W) + v_fmac ----
#pragma unroll
        for (int s = 0; s < 4; ++s) {
            float xr[32];
#pragma unroll
            for (int i = 0; i < 8; ++i) {
                const int f = s * 32 + i * 4;                  // float idx in row
                const int P = (rowOff + f * 4) ^ swz;          // swizzled byte offset
                const float4 xv = *(const float4*)(tbase + P);
                xr[i * 4 + 0] = xv.x; xr[i * 4 + 1] = xv.y;
                xr[i * 4 + 2] = xv.z; xr[i * 4 + 3] = xv.w;
            }
            // pure scalar-W FMA stream: no DS ops in flight here
            const float* wbase = Wrows + c * DC + s * 32;
#pragma unroll
            for (int kw = 0; kw < 8; ++kw) {
#pragma unroll
                for (int e = 0; e < 8; ++e) {
                    const float* wp = wbase + e * DDIM + kw * 4;
                    acc[e] = fmaf(xr[kw * 4 + 0], wp[0], acc[e]);
                    acc[e] = fmaf(xr[kw * 4 + 1], wp[1], acc[e]);
                    acc[e] = fmaf(xr[kw * 4 + 2], wp[2], acc[e]);
                    acc[e] = fmaf(xr[kw * 4 + 3], wp[3], acc[e]);
                }
            }
        }
        __syncthreads();   // staged chunk c+1 landed; everyone done with chunk c
    }

    // ---- gather the 4 wave-octets per token ----
#pragma unroll
    for (int e = 0; e < 8; ++e) res[w][lane][e] = acc[e];
    __syncthreads();

    if (tid < TOK_PER_BLK) {
        const int t = tid;
        const int tok = tokBase + t;

        float nz[16];
#pragma unroll
        for (int j = 0; j < 4; ++j) {
            const float4 v = *(const float4*)(noise + (size_t)tok * 16 + j * 4);
            nz[j * 4 + 0] = v.x; nz[j * 4 + 1] = v.y;
            nz[j * 4 + 2] = v.z; nz[j * 4 + 3] = v.w;
        }

        float logit[16];
#pragma unroll
        for (int e = 0; e < 16; ++e) {
            const float cl = res[e >> 3][t][e & 7];
            const float nl = res[2 + (e >> 3)][t][e & 7];
            const float sp = fmaxf(nl, 0.0f) + log1pf(expf(-fabsf(nl)));
            logit[e] = cl + nz[e] * sp * 0.01f;
        }

        float m = logit[0];
#pragma unroll
        for (int e = 1; e < 16; ++e) m = fmaxf(m, logit[e]);

        float g[16];
        float s = 0.0f;
#pragma unroll
        for (int e = 0; e < 16; ++e) { g[e] = expf(logit[e] - m); s += g[e]; }
        const float inv = 1.0f / s;
#pragma unroll
        for (int e = 0; e < 16; ++e) g[e] *= inv;

        // top-2, strict > so ties keep the lower index (matches lax.top_k)
        float v1 = -1.0f, v2 = -1.0f;
        int i1 = 0, i2 = 0;
#pragma unroll
        for (int e = 0; e < 16; ++e) {
            const float ge = g[e];
            if (ge > v1)      { v2 = v1; i2 = i1; v1 = ge; i1 = e; }
            else if (ge > v2) { v2 = ge; i2 = e; }
        }
        const float den = v1 + v2 + 1e-8f;
        out_gates[(size_t)tok * 2 + 0] = v1 / den;
        out_gates[(size_t)tok * 2 + 1] = v2 / den;
        out_idx[(size_t)tok * 2 + 0] = (float)i1;
        out_idx[(size_t)tok * 2 + 1] = (float)i2;

        // load = sum over tokens of gates: reduce across the 64 lanes of wave 0
#pragma unroll
        for (int e = 0; e < 16; ++e) {
            float v = g[e];
            for (int off = 32; off; off >>= 1) v += __shfl_xor(v, off, 64);
            if (lane == 0) atomicAdd(&out_load[e], v);
        }
    }
}

extern "C" void kernel_launch(void* const* d_in, const int* in_sizes, int n_in,
                              void* d_out, int out_size, void* d_ws, size_t ws_size,
                              hipStream_t stream) {
    (void)in_sizes; (void)n_in; (void)d_ws; (void)ws_size; (void)out_size;
    const float* x     = (const float*)d_in[0];
    const float* noise = (const float*)d_in[1];
    const float* Wg    = (const float*)d_in[2];
    const float* Wn    = (const float*)d_in[3];

    float* out       = (float*)d_out;
    float* out_gates = out;
    float* out_idx   = out + (size_t)N_TOK * 2;
    float* out_load  = out + (size_t)N_TOK * 4;

    // load region is accumulated with atomics -> zero it every call
    hipMemsetAsync(out_load, 0, NEXP * sizeof(float), stream);

    router_main<<<N_TOK / TOK_PER_BLK, THREADS, 0, stream>>>(
        x, noise, Wg, Wn, out_gates, out_idx, out_load);
}

// Round 4
// 116.766 us; speedup vs baseline: 1.9127x; 1.9048x over previous
//
#include <hip/hip_runtime.h>
#include <hip/hip_bf16.h>
#include <math.h>

#define N_TOK 32768
#define DDIM 1024
#define NEXP 16
#define TOK_PER_BLK 64
#define DC 128
#define NCHUNK (DDIM / DC)
#define THREADS 256
#define NBLK (N_TOK / TOK_PER_BLK)

// d_ws layout (floats): [0, 32768): repacked W  |  [32768, 32768+NBLK*16): per-block load partials
// Wre[oct][k4][e][j]: oct = wave octet (0:Wg e0-7, 1:Wg e8-15, 2:Wn e0-7, 3:Wn e8-15),
// k4 = k/4 (0..255), e = expert-in-octet, j = k%4.  Per k4: 32 contiguous floats.
__global__ __launch_bounds__(256) void repack_w(
    const float* __restrict__ Wg, const float* __restrict__ Wn, float* __restrict__ Wre)
{
    const int i = blockIdx.x * 256 + threadIdx.x;   // 32768 total
    const int j   = i & 3;
    const int e   = (i >> 2) & 7;
    const int k4  = (i >> 5) & 255;
    const int oct = i >> 13;
    const float* W = (oct & 2) ? Wn : Wg;
    Wre[i] = W[(size_t)((oct & 1) * 8 + e) * DDIM + k4 * 4 + j];
}

// out layout (floats): [0,65536) top2 gates, [65536,131072) top2 indices (as float),
// [131072,131088) load
__global__ __launch_bounds__(THREADS) void router_main(
    const float* __restrict__ x, const float* __restrict__ noise,
    const float* __restrict__ Wre,
    float* __restrict__ out_gates, float* __restrict__ out_idx,
    float* __restrict__ partials)
{
    __shared__ float tile[2][TOK_PER_BLK * DC];  // 2 x 32 KB, XOR-swizzled
    __shared__ float res[4][TOK_PER_BLK][8];     // 8 KB: per-wave dot results

    const int tid  = threadIdx.x;
    const int lane = tid & 63;
    const int w    = __builtin_amdgcn_readfirstlane(tid >> 6); // wave id, SGPR
    const int tokBase = blockIdx.x * TOK_PER_BLK;

    const float* wbase = Wre + (size_t)w * 8192;   // this wave's contiguous W stream

    float acc[8];
#pragma unroll
    for (int e = 0; e < 8; ++e) acc[e] = 0.0f;

    const int rowOff = lane * (DC * 4);        // 512 B per token row
    const int swz    = (lane & 31) << 4;

    // ---- staging helper (wave-uniform dest + pre-swizzled per-lane source) ----
    auto stage = [&](int buf, int c) {
#pragma unroll
        for (int i = 0; i < 8; ++i) {
            const int instr = w * 8 + i;              // 0..31
            const int P = instr * 1024 + lane * 16;   // physical byte offset in tile
            const int L = P ^ (((P >> 9) & 31) << 4); // logical byte offset (involution)
            const int t  = L >> 9;                    // token row
            const int dl = (L & 511) >> 2;            // float idx within row
            const float* src = x + (size_t)(tokBase + t) * DDIM + c * DC + dl;
            __builtin_amdgcn_global_load_lds(
                (const __attribute__((address_space(1))) void*)src,
                (__attribute__((address_space(3))) void*)((char*)&tile[buf][0] + instr * 1024),
                16, 0, 0);
        }
    };

    stage(0, 0);
    __syncthreads();

    for (int c = 0; c < NCHUNK; ++c) {
        const int cur = c & 1;
        if (c + 1 < NCHUNK) stage(cur ^ 1, c + 1);   // prefetch next chunk

        const char* tbase = (const char*)&tile[cur][0];

#pragma unroll
        for (int s = 0; s < 4; ++s) {
            // phase 1: x sub-chunk (32 k) LDS -> VGPRs
            float xr[32];
#pragma unroll
            for (int i = 0; i < 8; ++i) {
                const int f = s * 32 + i * 4;                  // float idx in row
                const int P = (rowOff + f * 4) ^ swz;          // swizzled byte offset
                const float4 xv = *(const float4*)(tbase + P);
                xr[i * 4 + 0] = xv.x; xr[i * 4 + 1] = xv.y;
                xr[i * 4 + 2] = xv.z; xr[i * 4 + 3] = xv.w;
            }
            // phase 2: W is a contiguous wave-uniform 1 KB stream for this sub-chunk
            const float* wp = wbase + (size_t)(c * 32 + s * 8) * 32;
#pragma unroll
            for (int kw = 0; kw < 8; ++kw) {
#pragma unroll
                for (int e = 0; e < 8; ++e) {
                    const float4 wv = *(const float4*)(wp + kw * 32 + e * 4);
                    acc[e] = fmaf(xr[kw * 4 + 0], wv.x, acc[e]);
                    acc[e] = fmaf(xr[kw * 4 + 1], wv.y, acc[e]);
                    acc[e] = fmaf(xr[kw * 4 + 2], wv.z, acc[e]);
                    acc[e] = fmaf(xr[kw * 4 + 3], wv.w, acc[e]);
                }
            }
        }
        __syncthreads();   // staged chunk c+1 landed; everyone done with chunk c
    }

    // ---- gather the 4 wave-octets per token ----
#pragma unroll
    for (int e = 0; e < 8; ++e) res[w][lane][e] = acc[e];
    __syncthreads();

    if (tid < TOK_PER_BLK) {
        const int t = tid;
        const int tok = tokBase + t;

        float nz[16];
#pragma unroll
        for (int j = 0; j < 4; ++j) {
            const float4 v = *(const float4*)(noise + (size_t)tok * 16 + j * 4);
            nz[j * 4 + 0] = v.x; nz[j * 4 + 1] = v.y;
            nz[j * 4 + 2] = v.z; nz[j * 4 + 3] = v.w;
        }

        float logit[16];
#pragma unroll
        for (int e = 0; e < 16; ++e) {
            const float cl = res[e >> 3][t][e & 7];
            const float nl = res[2 + (e >> 3)][t][e & 7];
            const float sp = fmaxf(nl, 0.0f) + log1pf(expf(-fabsf(nl)));
            logit[e] = cl + nz[e] * sp * 0.01f;
        }

        float m = logit[0];
#pragma unroll
        for (int e = 1; e < 16; ++e) m = fmaxf(m, logit[e]);

        float g[16];
        float s = 0.0f;
#pragma unroll
        for (int e = 0; e < 16; ++e) { g[e] = expf(logit[e] - m); s += g[e]; }
        const float inv = 1.0f / s;
#pragma unroll
        for (int e = 0; e < 16; ++e) g[e] *= inv;

        // top-2, strict > so ties keep the lower index (matches lax.top_k)
        float v1 = -1.0f, v2 = -1.0f;
        int i1 = 0, i2 = 0;
#pragma unroll
        for (int e = 0; e < 16; ++e) {
            const float ge = g[e];
            if (ge > v1)      { v2 = v1; i2 = i1; v1 = ge; i1 = e; }
            else if (ge > v2) { v2 = ge; i2 = e; }
        }
        const float den = v1 + v2 + 1e-8f;
        out_gates[(size_t)tok * 2 + 0] = v1 / den;
        out_gates[(size_t)tok * 2 + 1] = v2 / den;
        out_idx[(size_t)tok * 2 + 0] = (float)i1;
        out_idx[(size_t)tok * 2 + 1] = (float)i2;

        // per-block load partials: butterfly reduce (result lands in all lanes)
        float parts[16];
#pragma unroll
        for (int e = 0; e < 16; ++e) {
            float v = g[e];
#pragma unroll
            for (int off = 32; off; off >>= 1) v += __shfl_xor(v, off, 64);
            parts[e] = v;
        }
        if (lane == 0) {
            float4* pp = (float4*)(partials + (size_t)blockIdx.x * 16);
            pp[0] = make_float4(parts[0],  parts[1],  parts[2],  parts[3]);
            pp[1] = make_float4(parts[4],  parts[5],  parts[6],  parts[7]);
            pp[2] = make_float4(parts[8],  parts[9],  parts[10], parts[11]);
            pp[3] = make_float4(parts[12], parts[13], parts[14], parts[15]);
        }
    }
}

__global__ __launch_bounds__(64) void reduce_load(
    const float* __restrict__ partials, float* __restrict__ out_load)
{
    const int lane = threadIdx.x;
    float loc[16];
#pragma unroll
    for (int e = 0; e < 16; ++e) loc[e] = 0.0f;
    for (int b = lane; b < NBLK; b += 64) {          // coalesced: lane -> 64B chunk
        const float4* p = (const float4*)(partials + (size_t)b * 16);
#pragma unroll
        for (int j = 0; j < 4; ++j) {
            const float4 v = p[j];
            loc[j * 4 + 0] += v.x; loc[j * 4 + 1] += v.y;
            loc[j * 4 + 2] += v.z; loc[j * 4 + 3] += v.w;
        }
    }
#pragma unroll
    for (int e = 0; e < 16; ++e) {
        float v = loc[e];
#pragma unroll
        for (int off = 32; off; off >>= 1) v += __shfl_xor(v, off, 64);
        if (lane == 0) out_load[e] = v;
    }
}

extern "C" void kernel_launch(void* const* d_in, const int* in_sizes, int n_in,
                              void* d_out, int out_size, void* d_ws, size_t ws_size,
                              hipStream_t stream) {
    (void)in_sizes; (void)n_in; (void)ws_size; (void)out_size;
    const float* x     = (const float*)d_in[0];
    const float* noise = (const float*)d_in[1];
    const float* Wg    = (const float*)d_in[2];
    const float* Wn    = (const float*)d_in[3];

    float* out       = (float*)d_out;
    float* out_gates = out;
    float* out_idx   = out + (size_t)N_TOK * 2;
    float* out_load  = out + (size_t)N_TOK * 4;

    float* Wre      = (float*)d_ws;                 // 32768 floats
    float* partials = (float*)d_ws + 32768;         // NBLK*16 floats

    repack_w<<<128, 256, 0, stream>>>(Wg, Wn, Wre);  // 32768 elements / 256 threads
    router_main<<<NBLK, THREADS, 0, stream>>>(
        x, noise, Wre, out_gates, out_idx, partials);
    reduce_load<<<1, 64, 0, stream>>>(partials, out_load);
}

// Round 7
// 40.818 us; speedup vs baseline: 5.4716x; 2.8606x over previous
//
#include <hip/hip_runtime.h>
#include <hip/hip_bf16.h>
#include <math.h>

#define N_TOK 32768
#define DDIM 1024
#define NEXP 16
#define THREADS 256
#define TOK_PER_WAVE 16
#define TOK_PER_BLK 64
#define NBLK (N_TOK / TOK_PER_BLK)   // 512
#define KSTEPS (DDIM / 32)           // 32

typedef __attribute__((ext_vector_type(8))) short bf16x8;
typedef __attribute__((ext_vector_type(4))) float f32x4;

__device__ inline short f2bf(float f) {            // RNE f32->bf16 (inputs are normal)
    unsigned u = __builtin_bit_cast(unsigned, f);
    u += 0x7fffu + ((u >> 16) & 1u);
    return (short)(u >> 16);
}

// Wfrag[s][tile][lane][j] (bf16): A-fragment stream for mfma_f32_16x16x32_bf16.
// row m = tile*16 + (lane&15)  (tile0 = Wg e0-15, tile1 = Wn e0-15)
// k     = s*32 + (lane>>4)*8 + j
__global__ __launch_bounds__(256) void make_wfrag(
    const float* __restrict__ Wg, const float* __restrict__ Wn,
    unsigned short* __restrict__ Wfrag)
{
    const int i    = blockIdx.x * 256 + threadIdx.x;   // 32768 total
    const int j    = i & 7;
    const int lane = (i >> 3) & 63;
    const int tile = (i >> 9) & 1;
    const int s    = i >> 10;
    const int k    = s * 32 + (lane >> 4) * 8 + j;
    const float* W = tile ? Wn : Wg;
    Wfrag[i] = (unsigned short)f2bf(W[(size_t)(lane & 15) * DDIM + k]);
}

// out layout (floats): [0,65536) top2 gates, [65536,131072) top2 indices (as float),
// [131072,131088) load
__global__ __launch_bounds__(THREADS) void router_mfma(
    const float* __restrict__ x, const float* __restrict__ noise,
    const unsigned short* __restrict__ Wfrag,
    float* __restrict__ out_gates, float* __restrict__ out_idx,
    float* __restrict__ partials)
{
    __shared__ float blk_load[NEXP];
    const int tid  = threadIdx.x;
    const int lane = tid & 63;
    const int w    = tid >> 6;
    if (tid < NEXP) blk_load[tid] = 0.0f;
    __syncthreads();

    const int tok = blockIdx.x * TOK_PER_BLK + w * TOK_PER_WAVE + (lane & 15);
    const int grp = lane >> 4;                       // 4-lane group id for this token

    const float*          xb = x + (size_t)tok * DDIM + grp * 8;
    const unsigned short* wb = Wfrag + (size_t)lane * 8;

    f32x4 acc0 = {0.f, 0.f, 0.f, 0.f};              // D rows 0-15  (gate logits)
    f32x4 acc1 = {0.f, 0.f, 0.f, 0.f};              // D rows 16-31 (noise logits)

#pragma unroll 4
    for (int s = 0; s < KSTEPS; ++s) {
        const float4 lo = *(const float4*)(xb + s * 32);
        const float4 hi = *(const float4*)(xb + s * 32 + 4);
        const bf16x8 a0 = *(const bf16x8*)(wb + (size_t)(s * 2 + 0) * 512);
        const bf16x8 a1 = *(const bf16x8*)(wb + (size_t)(s * 2 + 1) * 512);
        bf16x8 b;
        b[0] = f2bf(lo.x); b[1] = f2bf(lo.y); b[2] = f2bf(lo.z); b[3] = f2bf(lo.w);
        b[4] = f2bf(hi.x); b[5] = f2bf(hi.y); b[6] = f2bf(hi.z); b[7] = f2bf(hi.w);
        acc0 = __builtin_amdgcn_mfma_f32_16x16x32_bf16(a0, b, acc0, 0, 0, 0);
        acc1 = __builtin_amdgcn_mfma_f32_16x16x32_bf16(a1, b, acc1, 0, 0, 0);
    }

    // ---- epilogue: lane l holds, for token tok, experts e = grp*4 + r (r=0..3):
    //      clean logit acc0[r], noise logit acc1[r] ----
    const float4 nz4 = *(const float4*)(noise + (size_t)tok * NEXP + grp * 4);
    const float nzv[4] = {nz4.x, nz4.y, nz4.z, nz4.w};

    float lg[4];
#pragma unroll
    for (int r = 0; r < 4; ++r) {
        const float cl = acc0[r];
        const float nl = acc1[r];
        const float sp = fmaxf(nl, 0.0f) + log1pf(expf(-fabsf(nl)));
        lg[r] = cl + nzv[r] * sp * 0.01f;
    }

    // softmax over the 16 experts of this token (4 lanes x 4 regs, butterfly xor 16/32)
    float m = fmaxf(fmaxf(lg[0], lg[1]), fmaxf(lg[2], lg[3]));
    m = fmaxf(m, __shfl_xor(m, 16, 64));
    m = fmaxf(m, __shfl_xor(m, 32, 64));

    float p[4];
    float ssum = 0.0f;
#pragma unroll
    for (int r = 0; r < 4; ++r) { p[r] = expf(lg[r] - m); ssum += p[r]; }
    ssum += __shfl_xor(ssum, 16, 64);
    ssum += __shfl_xor(ssum, 32, 64);
    const float inv = 1.0f / ssum;

    float g[4];
#pragma unroll
    for (int r = 0; r < 4; ++r) g[r] = p[r] * inv;

    // local top-2 over this lane's 4 experts (tie -> lower index)
    float v1 = -1.0f, v2 = -1.0f;
    int   i1 = 0,     i2 = 0;
#pragma unroll
    for (int r = 0; r < 4; ++r) {
        const float ge = g[r];
        const int   e  = grp * 4 + r;
        if (ge > v1)      { v2 = v1; i2 = i1; v1 = ge; i1 = e; }
        else if (ge > v2) { v2 = ge; i2 = e; }
    }
    // butterfly merge across the 4 lanes of this token
#pragma unroll
    for (int off = 16; off <= 32; off <<= 1) {
        const float ov1 = __shfl_xor(v1, off, 64);
        const float ov2 = __shfl_xor(v2, off, 64);
        const int   oi1 = __shfl_xor(i1, off, 64);
        const int   oi2 = __shfl_xor(i2, off, 64);
        const bool aWins = (v1 > ov1) || (v1 == ov1 && i1 < oi1);
        float nv1, nv2; int ni1, ni2;
        if (aWins) {
            nv1 = v1; ni1 = i1;
            const bool bNext = (ov1 > v2) || (ov1 == v2 && oi1 < i2);
            nv2 = bNext ? ov1 : v2;  ni2 = bNext ? oi1 : i2;
        } else {
            nv1 = ov1; ni1 = oi1;
            const bool aNext = (v1 > ov2) || (v1 == ov2 && i1 < oi2);
            nv2 = aNext ? v1 : ov2;  ni2 = aNext ? i1 : oi2;
        }
        v1 = nv1; v2 = nv2; i1 = ni1; i2 = ni2;
    }
    if (grp == 0) {
        const float den = v1 + v2 + 1e-8f;
        out_gates[(size_t)tok * 2 + 0] = v1 / den;
        out_gates[(size_t)tok * 2 + 1] = v2 / den;
        out_idx[(size_t)tok * 2 + 0] = (float)i1;
        out_idx[(size_t)tok * 2 + 1] = (float)i2;
    }

    // load partials: sum g over the 16 tokens of this wave (butterfly over lane&15)
#pragma unroll
    for (int r = 0; r < 4; ++r) {
        float v = g[r];
        v += __shfl_xor(v, 1, 64);
        v += __shfl_xor(v, 2, 64);
        v += __shfl_xor(v, 4, 64);
        v += __shfl_xor(v, 8, 64);
        if ((lane & 15) == 0) atomicAdd(&blk_load[grp * 4 + r], v);
    }
    __syncthreads();
    if (tid < NEXP) partials[(size_t)blockIdx.x * NEXP + tid] = blk_load[tid];
}

__global__ __launch_bounds__(64) void reduce_load(
    const float* __restrict__ partials, float* __restrict__ out_load)
{
    const int lane = threadIdx.x;
    float loc[16];
#pragma unroll
    for (int e = 0; e < 16; ++e) loc[e] = 0.0f;
    for (int b = lane; b < NBLK; b += 64) {
        const float4* p = (const float4*)(partials + (size_t)b * 16);
#pragma unroll
        for (int j = 0; j < 4; ++j) {
            const float4 v = p[j];
            loc[j * 4 + 0] += v.x; loc[j * 4 + 1] += v.y;
            loc[j * 4 + 2] += v.z; loc[j * 4 + 3] += v.w;
        }
    }
#pragma unroll
    for (int e = 0; e < 16; ++e) {
        float v = loc[e];
#pragma unroll
        for (int off = 32; off; off >>= 1) v += __shfl_xor(v, off, 64);
        if (lane == 0) out_load[e] = v;
    }
}

extern "C" void kernel_launch(void* const* d_in, const int* in_sizes, int n_in,
                              void* d_out, int out_size, void* d_ws, size_t ws_size,
                              hipStream_t stream) {
    (void)in_sizes; (void)n_in; (void)ws_size; (void)out_size;
    const float* x     = (const float*)d_in[0];
    const float* noise = (const float*)d_in[1];
    const float* Wg    = (const float*)d_in[2];
    const float* Wn    = (const float*)d_in[3];

    float* out       = (float*)d_out;
    float* out_gates = out;
    float* out_idx   = out + (size_t)N_TOK * 2;
    float* out_load  = out + (size_t)N_TOK * 4;

    unsigned short* Wfrag = (unsigned short*)d_ws;                 // 64 KB
    float* partials = (float*)((char*)d_ws + 65536);               // NBLK*16 floats

    make_wfrag<<<128, 256, 0, stream>>>(Wg, Wn, Wfrag);            // 32768 elems
    router_mfma<<<NBLK, THREADS, 0, stream>>>(
        x, noise, Wfrag, out_gates, out_idx, partials);
    reduce_load<<<1, 64, 0, stream>>>(partials, out_load);
}